// Round 1
// baseline (479.535 us; speedup 1.0000x reference)
//
#include <hip/hip_runtime.h>

#define B 8
#define C 256
#define HW 16384
#define NSEG 256
#define NBLK (B * C)   // 2048 main-kernel blocks

// ws layout:
//   [0, 8192)            : int   counts[B][NSEG]
//   [8192, 8192+131072)  : u8    ids[B][HW]
//   [139264, 139264+16384): double partials[NBLK]

__global__ __launch_bounds__(1024) void prep_kernel(const float* __restrict__ mask,
                                                    int* __restrict__ counts,
                                                    unsigned char* __restrict__ ids) {
    __shared__ int hist[NSEG];
    const int b = blockIdx.x;
    const int t = threadIdx.x;
    if (t < NSEG) hist[t] = 0;
    __syncthreads();

    const float4* m4 = (const float4*)(mask + (size_t)b * HW);
    uchar4* o4 = (uchar4*)(ids + (size_t)b * HW);
    // HW/4 = 4096 float4s, 1024 threads -> 4 iterations
    for (int j = 0; j < HW / 4 / 1024; ++j) {
        int idx = j * 1024 + t;
        float4 v = m4[idx];
        int i0 = (int)v.x, i1 = (int)v.y, i2 = (int)v.z, i3 = (int)v.w;
        o4[idx] = make_uchar4((unsigned char)i0, (unsigned char)i1,
                              (unsigned char)i2, (unsigned char)i3);
        atomicAdd(&hist[i0], 1);
        atomicAdd(&hist[i1], 1);
        atomicAdd(&hist[i2], 1);
        atomicAdd(&hist[i3], 1);
    }
    __syncthreads();
    if (t < NSEG) counts[b * NSEG + t] = hist[t];
}

__device__ __forceinline__ float sigmoidf(float x) {
    return 1.0f / (1.0f + __expf(-x));
}

__global__ __launch_bounds__(256) void main_kernel(const float* __restrict__ x,
                                                   const unsigned char* __restrict__ ids,
                                                   const int* __restrict__ counts,
                                                   double* __restrict__ partials) {
    __shared__ float sS[NSEG];
    __shared__ float sQ[NSEG];
    __shared__ double wsum[4];

    const int bid = blockIdx.x;
    const int b = bid >> 8;      // / C
    const int c = bid & 255;     // % C
    const int t = threadIdx.x;

    sS[t] = 0.0f;
    sQ[t] = 0.0f;
    __syncthreads();

    const float4* x4 = (const float4*)(x + (size_t)(b * C + c) * HW);
    const uchar4* id4 = (const uchar4*)(ids + (size_t)b * HW);

    // HW/4 = 4096 float4s, 256 threads -> 16 iterations
    for (int j = 0; j < HW / 4 / 256; ++j) {
        int idx = j * 256 + t;
        float4 v = x4[idx];
        uchar4 s = id4[idx];
        float e0 = sigmoidf(v.x);
        float e1 = sigmoidf(v.y);
        float e2 = sigmoidf(v.z);
        float e3 = sigmoidf(v.w);
        atomicAdd(&sS[s.x], e0);
        atomicAdd(&sQ[s.x], e0 * e0);
        atomicAdd(&sS[s.y], e1);
        atomicAdd(&sQ[s.y], e1 * e1);
        atomicAdd(&sS[s.z], e2);
        atomicAdd(&sQ[s.z], e2 * e2);
        atomicAdd(&sS[s.w], e3);
        atomicAdd(&sQ[s.w], e3 * e3);
    }
    __syncthreads();

    // per-segment combine (segment t, skip background 255)
    double p = 0.0;
    if (t < NSEG - 1) {
        float n = (float)counts[b * NSEG + t];
        if (n < 1.0f) n = 1.0f;
        double S = (double)sS[t];
        double Q = (double)sQ[t];
        p = Q - S * S / (double)n;
    }
    // block reduce (4 waves of 64)
    #pragma unroll
    for (int off = 32; off > 0; off >>= 1) p += __shfl_down(p, off);
    const int lane = t & 63, w = t >> 6;
    if (lane == 0) wsum[w] = p;
    __syncthreads();
    if (t == 0) partials[bid] = wsum[0] + wsum[1] + wsum[2] + wsum[3];
}

__global__ __launch_bounds__(256) void final_kernel(const double* __restrict__ partials,
                                                    float* __restrict__ out) {
    __shared__ double wsum[4];
    const int t = threadIdx.x;
    double p = 0.0;
    #pragma unroll
    for (int j = 0; j < NBLK / 256; ++j) p += partials[j * 256 + t];
    #pragma unroll
    for (int off = 32; off > 0; off >>= 1) p += __shfl_down(p, off);
    const int lane = t & 63, w = t >> 6;
    if (lane == 0) wsum[w] = p;
    __syncthreads();
    if (t == 0) {
        double total = wsum[0] + wsum[1] + wsum[2] + wsum[3];
        out[0] = (float)(total / (double)((size_t)B * C * HW));
    }
}

extern "C" void kernel_launch(void* const* d_in, const int* in_sizes, int n_in,
                              void* d_out, int out_size, void* d_ws, size_t ws_size,
                              hipStream_t stream) {
    const float* x = (const float*)d_in[0];
    const float* mask = (const float*)d_in[1];
    float* out = (float*)d_out;

    char* ws = (char*)d_ws;
    int* counts = (int*)ws;                                  // 8 KiB
    unsigned char* ids = (unsigned char*)(ws + 8192);        // 128 KiB
    double* partials = (double*)(ws + 139264);               // 16 KiB

    prep_kernel<<<B, 1024, 0, stream>>>(mask, counts, ids);
    main_kernel<<<NBLK, 256, 0, stream>>>(x, ids, counts, partials);
    final_kernel<<<1, 256, 0, stream>>>(partials, out);
}

// Round 2
// 220.193 us; speedup vs baseline: 2.1778x; 2.1778x over previous
//
#include <hip/hip_runtime.h>

#define B 8
#define C 256
#define HW 16384
#define NSEG 256
#define NBLK (B * C)   // 2048 main-kernel blocks

// ws layout:
//   [0, 8192)              : int    counts[B][NSEG]
//   [8192, 16384)          : int    starts[B][NSEG]
//   [16384, 16384+262144)  : u16    sortpos[B][HW]     (position of pixel p in segment-sorted order)
//   [278528, 278528+16384) : double partials[NBLK]

// LDS word swizzle: break the stride-64-float same-bank pattern in phase-2 reads
__device__ __forceinline__ int swz(int w) { return w + (w >> 5); }
#define SE_WORDS (HW + HW / 32)   // 16896 words = 67584 B

__global__ __launch_bounds__(1024) void prep_kernel(const float* __restrict__ mask,
                                                    int* __restrict__ counts,
                                                    int* __restrict__ starts,
                                                    unsigned short* __restrict__ sortpos) {
    __shared__ int hist[NSEG];
    __shared__ int scan[NSEG];
    __shared__ int offs[NSEG];
    __shared__ unsigned char idbuf[HW];   // 16 KiB

    const int b = blockIdx.x;
    const int t = threadIdx.x;
    if (t < NSEG) hist[t] = 0;
    __syncthreads();

    const float4* m4 = (const float4*)(mask + (size_t)b * HW);
    uchar4* ib4 = (uchar4*)idbuf;
    // HW/4 = 4096 float4s, 1024 threads -> 4 iterations
    for (int j = 0; j < HW / 4 / 1024; ++j) {
        int idx = j * 1024 + t;
        float4 v = m4[idx];
        int i0 = (int)v.x, i1 = (int)v.y, i2 = (int)v.z, i3 = (int)v.w;
        ib4[idx] = make_uchar4((unsigned char)i0, (unsigned char)i1,
                               (unsigned char)i2, (unsigned char)i3);
        atomicAdd(&hist[i0], 1);
        atomicAdd(&hist[i1], 1);
        atomicAdd(&hist[i2], 1);
        atomicAdd(&hist[i3], 1);
    }
    __syncthreads();

    // inclusive scan over 256 counts (Hillis-Steele, first 256 threads)
    if (t < NSEG) scan[t] = hist[t];
    __syncthreads();
    for (int off = 1; off < NSEG; off <<= 1) {
        int v = 0;
        if (t < NSEG && t >= off) v = scan[t - off];
        __syncthreads();
        if (t < NSEG) scan[t] += v;
        __syncthreads();
    }
    if (t < NSEG) {
        int st = scan[t] - hist[t];          // exclusive
        counts[b * NSEG + t] = hist[t];
        starts[b * NSEG + t] = st;
        offs[t] = st;
    }
    __syncthreads();

    // assign each pixel its slot in segment-sorted order
    for (int j = 0; j < HW / 1024; ++j) {
        int p = j * 1024 + t;
        int id = idbuf[p];
        int pos = atomicAdd(&offs[id], 1);
        sortpos[(size_t)b * HW + p] = (unsigned short)pos;
    }
}

__device__ __forceinline__ float sigmoidf(float x) {
    return 1.0f / (1.0f + __expf(-x));
}

__global__ __launch_bounds__(256) void main_kernel(const float* __restrict__ x,
                                                   const unsigned short* __restrict__ sortpos,
                                                   const int* __restrict__ counts,
                                                   const int* __restrict__ starts,
                                                   double* __restrict__ partials) {
    __shared__ float se[SE_WORDS];   // sigmoid values in segment-sorted order (swizzled)
    __shared__ double wsum[4];

    const int bid = blockIdx.x;
    const int b = bid >> 8;      // / C
    const int c = bid & 255;     // % C
    const int t = threadIdx.x;

    const float4* x4 = (const float4*)(x + (size_t)(b * C + c) * HW);
    const ushort4* sp4 = (const ushort4*)(sortpos + (size_t)b * HW);

    // Phase 1: coalesced read, sigmoid, plain scatter into sorted LDS slots
    for (int j = 0; j < HW / 4 / 256; ++j) {   // 16 iterations
        int idx = j * 256 + t;
        float4 v = x4[idx];
        ushort4 s = sp4[idx];
        se[swz((int)s.x)] = sigmoidf(v.x);
        se[swz((int)s.y)] = sigmoidf(v.y);
        se[swz((int)s.z)] = sigmoidf(v.z);
        se[swz((int)s.w)] = sigmoidf(v.w);
    }
    __syncthreads();

    // Phase 2: thread t reduces segment t's contiguous run — registers only
    const int n  = counts[b * NSEG + t];
    const int st = starts[b * NSEG + t];
    float S = 0.0f, Q = 0.0f;
    if (t < NSEG - 1) {            // skip background segment 255
        for (int j = 0; j < n; ++j) {
            float e = se[swz(st + j)];
            S += e;
            Q += e * e;
        }
    }
    double p = 0.0;
    if (t < NSEG - 1 && n > 0) {
        p = (double)Q - (double)S * (double)S / (double)n;
    }

    // block reduce (4 waves of 64)
    #pragma unroll
    for (int off = 32; off > 0; off >>= 1) p += __shfl_down(p, off);
    const int lane = t & 63, w = t >> 6;
    if (lane == 0) wsum[w] = p;
    __syncthreads();
    if (t == 0) partials[bid] = wsum[0] + wsum[1] + wsum[2] + wsum[3];
}

__global__ __launch_bounds__(256) void final_kernel(const double* __restrict__ partials,
                                                    float* __restrict__ out) {
    __shared__ double wsum[4];
    const int t = threadIdx.x;
    double p = 0.0;
    #pragma unroll
    for (int j = 0; j < NBLK / 256; ++j) p += partials[j * 256 + t];
    #pragma unroll
    for (int off = 32; off > 0; off >>= 1) p += __shfl_down(p, off);
    const int lane = t & 63, w = t >> 6;
    if (lane == 0) wsum[w] = p;
    __syncthreads();
    if (t == 0) {
        double total = wsum[0] + wsum[1] + wsum[2] + wsum[3];
        out[0] = (float)(total / (double)((size_t)B * C * HW));
    }
}

extern "C" void kernel_launch(void* const* d_in, const int* in_sizes, int n_in,
                              void* d_out, int out_size, void* d_ws, size_t ws_size,
                              hipStream_t stream) {
    const float* x = (const float*)d_in[0];
    const float* mask = (const float*)d_in[1];
    float* out = (float*)d_out;

    char* ws = (char*)d_ws;
    int* counts = (int*)ws;                                    // 8 KiB
    int* starts = (int*)(ws + 8192);                           // 8 KiB
    unsigned short* sortpos = (unsigned short*)(ws + 16384);   // 256 KiB
    double* partials = (double*)(ws + 278528);                 // 16 KiB

    prep_kernel<<<B, 1024, 0, stream>>>(mask, counts, starts, sortpos);
    main_kernel<<<NBLK, 256, 0, stream>>>(x, sortpos, counts, starts, partials);
    final_kernel<<<1, 256, 0, stream>>>(partials, out);
}